// Round 3
// baseline (453.951 us; speedup 1.0000x reference)
//
#include <hip/hip_runtime.h>
#include <math.h>

#define HW 512
#define MASK 511
#define IMG (512*512)
#define NSTEP 16
#define NSLICE 17

#define TILE_Y 64
#define TILE_X 64
#define IN_Y 84            // rows [Y0-10, Y0+74)
#define IN_X_ST 88         // staged floats/row: gcols [X0-12, X0+76)
#define IN_XP 92           // padded row stride: 23 granules (odd) -> no bank conflict
#define LDS_WORDS (IN_Y * IN_XP)   // 7728 words = 30.2 KiB

#define WROW 24            // padded weight row stride in ws (16B-aligned rows, pads = 0)
typedef float v2 __attribute__((ext_vector_type(2)));

__global__ void prep_kernel(const float* __restrict__ w1,
                            const float* __restrict__ w2,
                            const float* __restrict__ w3,
                            float* __restrict__ ws) {
    int i = threadIdx.x;
    for (int idx = i; idx < 21 * WROW; idx += blockDim.x) {
        int r = idx / WROW, c = idx - r * WROW;
        ws[idx] = (c < 21) ? w1[r * 21 + c] : 0.f;   // pad cols 21..23 = 0
    }
    if (i == 0) {
        // 1->10->1 MLP on nonneg scalar collapses: C = sum_o w3[o]*max(w2[o],0)
        float c = 0.f;
        for (int o = 0; o < 10; ++o) c += w3[o] * fmaxf(w2[o], 0.f);
        ws[504] = c;
    }
}

__global__ void copy_kernel(const float* __restrict__ x, float* __restrict__ out) {
    int i = blockIdx.x * blockDim.x + threadIdx.x;   // float4 index
    if (i < 8 * 65536) {
        const float4* in4 = (const float4*)x;
        float4* out4 = (float4*)out;
        int b = i >> 16;
        int off = i & 65535;
        out4[(size_t)b * (NSLICE * 65536) + off] = in4[i];
    }
}

__global__ __launch_bounds__(256, 2)
void step_kernel(const float* __restrict__ state_base,
                 float* __restrict__ out_base,
                 const float* __restrict__ ws,
                 int t) {
    __shared__ float tile[LDS_WORDS];
    const int tx = threadIdx.x;        // 0..7  -> 8 cols each
    const int ty = threadIdx.y;        // 0..31 -> 2 rows each
    const int tid = tx + (ty << 3);
    const int X0 = blockIdx.x * TILE_X;
    const int Y0 = blockIdx.y * TILE_Y;
    const int b  = blockIdx.z;

    const float* __restrict__ in  = state_base + (size_t)(b * NSLICE + (t - 1)) * IMG;
    float* __restrict__ outp      = out_base   + (size_t)(b * NSLICE + t) * IMG;

    // ---- stage 84 x 88 (stride 92), float4 granularity, wrap-safe ----
    for (int j = tid; j < IN_Y * (IN_X_ST / 4); j += 256) {   // 84*22 = 1848
        int r = j / (IN_X_ST / 4);
        int k = j - r * (IN_X_ST / 4);
        int gr = (Y0 + r - 10) & MASK;
        int gc = (X0 + 4 * k - 12) & MASK;   // mult of 4, never crosses row end
        *(float4*)&tile[r * IN_XP + 4 * k] = *(const float4*)&in[gr * HW + gc];
    }
    __syncthreads();

    const int c0 = tx << 3;            // window base col in LDS (16B-aligned)
    const int r0 = ty << 1;            // LDS row for rr=0

    // acc[cc] = (sum over even dx, sum over odd dx) for output column cc
    v2 acc0[8], acc1[8];
    #pragma unroll
    for (int cc = 0; cc < 8; ++cc) { acc0[cc] = (v2)(0.f); acc1[cc] = (v2)(0.f); }

    v2 wA[11], wB[11];
    float win[32];
    v2 O[15];

    auto load_wrow = [&](v2* w, int rr) {
        const float4* p4 = (const float4*)(ws + rr * WROW);
        #pragma unroll
        for (int k = 0; k < 5; ++k) {
            float4 q = p4[k];
            w[2*k]   = (v2){q.x, q.y};
            w[2*k+1] = (v2){q.z, q.w};
        }
        w[10] = *(const v2*)(ws + rr * WROW + 20);   // (w[20], 0-pad)
    };
    auto load_win = [&](int rr) {
        const float* trow = &tile[(r0 + rr) * IN_XP + c0];
        #pragma unroll
        for (int k = 0; k < 8; ++k) {
            float4 q = *(const float4*)&trow[4 * k];
            win[4*k] = q.x; win[4*k+1] = q.y; win[4*k+2] = q.z; win[4*k+3] = q.w;
        }
    };
    auto build_O = [&]() {
        #pragma unroll
        for (int q = 1; q <= 14; ++q) O[q] = (v2){win[2*q+1], win[2*q+2]};
    };
    // win index for (cc,dx) is cc+dx+2; pair over (dx=2k, 2k+1):
    //   col pair (cc, cc+1), q = k + cc/2 + 1:  acc[cc] <- E[q], acc[cc+1] <- O[q]
    auto conv = [&](v2* acc, const v2* w) {
        #pragma unroll
        for (int k = 0; k < 11; ++k) {
            #pragma unroll
            for (int cc = 0; cc < 8; cc += 2) {
                int q = k + (cc >> 1) + 1;
                v2 e = (v2){win[2*q], win[2*q+1]};
                acc[cc]   = __builtin_elementwise_fma(w[k], e,    acc[cc]);
                acc[cc+1] = __builtin_elementwise_fma(w[k], O[q], acc[cc+1]);
            }
        }
    };

    // rr loop: input row r0+rr; out0 uses weight row rr, out1 uses rr-1
    load_wrow(wB, 0);
    load_win(0); build_O();
    conv(acc0, wB);
    for (int i = 0; i < 10; ++i) {
        int rr = 2 * i + 1;
        load_wrow(wA, rr);
        load_win(rr); build_O();
        conv(acc0, wA);
        conv(acc1, wB);
        load_wrow(wB, rr + 1);
        load_win(rr + 1); build_O();
        conv(acc0, wB);
        conv(acc1, wA);
    }
    load_win(21); build_O();
    conv(acc1, wB);                    // wB holds weight row 20

    const float C = ws[504];
    auto epilogue = [&](v2* acc, int o) {
        const float* crow = &tile[(r0 + 10 + o) * IN_XP + c0 + 12];  // center x
        float4 cx0 = *(const float4*)&crow[0];
        float4 cx1 = *(const float4*)&crow[4];
        float ctr[8] = {cx0.x, cx0.y, cx0.z, cx0.w, cx1.x, cx1.y, cx1.z, cx1.w};
        float res[8];
        #pragma unroll
        for (int cc = 0; cc < 8; ++cc) {
            float h  = acc[cc].x + acc[cc].y;
            float a  = ctr[cc] + C * fmaxf(h, 0.f);
            float ax = fabsf(a);
            float e  = __expf(2.f * ax);                   // tanh(|a|) = 1 - 2/(e+1)
            float r  = 1.f - 2.f * __builtin_amdgcn_rcpf(e + 1.f);
            res[cc]  = copysignf(r, a);
        }
        int row = Y0 + r0 + o;
        float4* po = (float4*)&outp[(size_t)row * HW + X0 + c0];
        po[0] = make_float4(res[0], res[1], res[2], res[3]);
        po[1] = make_float4(res[4], res[5], res[6], res[7]);
    };
    epilogue(acc0, 0);
    epilogue(acc1, 1);
}

extern "C" void kernel_launch(void* const* d_in, const int* in_sizes, int n_in,
                              void* d_out, int out_size, void* d_ws, size_t ws_size,
                              hipStream_t stream) {
    const float* x  = (const float*)d_in[0];
    const float* w1 = (const float*)d_in[1];
    const float* w2 = (const float*)d_in[2];
    const float* w3 = (const float*)d_in[3];
    float* out = (float*)d_out;
    float* ws  = (float*)d_ws;

    prep_kernel<<<1, 128, 0, stream>>>(w1, w2, w3, ws);
    copy_kernel<<<2048, 256, 0, stream>>>(x, out);

    dim3 grid(HW / TILE_X, HW / TILE_Y, 8);   // 8 x 8 x 8 = 512 blocks = 2/CU
    dim3 block(8, 32);
    for (int t = 1; t <= NSTEP; ++t)          // steps = 16 (fixed by setup_inputs)
        step_kernel<<<grid, block, 0, stream>>>(out, out, ws, t);
}